// Round 13
// baseline (651.730 us; speedup 1.0000x reference)
//
#include <hip/hip_runtime.h>
#include <cstddef>
#include <math.h>

// ---------------- problem constants ----------------
#define B_   2
#define L_   2048
#define D_   512
#define E_   768
static const size_t LL   = (size_t)L_ * L_;
static const size_t SLOT = (size_t)B_ * LL;

#define QK_N  ((size_t)B_ * L_ * D_)       // 2097152
#define G1_N  ((size_t)512 * 512)          // 262144
#define G_N   ((size_t)6 * G1_N)           // 1572864
#define U_N   ((size_t)6 * L_ * D_)        // 6291456
#define X_N   ((size_t)4096 * 768)         // 3145728
#define W_N   ((size_t)512 * 768)          // 393216

typedef unsigned short u16;
typedef __attribute__((ext_vector_type(8)))  _Float16 half8;   // 8 f16 (4 VGPR)
typedef __attribute__((ext_vector_type(16))) float f32x16;     // 32x32 C/D

// ---------------- f16x2 split of fp32, scaled residual ------------------------
// f = h0 + h1/4096 + r2, |r2| <= |f|*2^-24 (h1 exact by Sterbenz + pow2 scale;
// stays in f16 normal range). Proven absmax 0.0 in round 12.
__device__ __forceinline__ void split2(float f, u16& h0, u16& h1) {
    _Float16 a = (_Float16)f;
    _Float16 b = (_Float16)((f - (float)a) * 4096.0f);
    h0 = __builtin_bit_cast(u16, a);
    h1 = __builtin_bit_cast(u16, b);
}

#define BKP 40   // LDS row pitch in u16 (pad: frag reads ~2-way banks)

// ============ plane-based stagers (16B global loads, 2 planes) ================
__device__ __forceinline__ void pstage_MK(const u16* __restrict__ P, size_t pstride, int ld,
                                          int r0, int k0, int tid, u16 S[2][64][BKP]) {
    int m = tid >> 2, kq = (tid & 3) << 3;                  // 8 u16 = 16B per thread
#pragma unroll
    for (int s = 0; s < 2; ++s) {
        const uint4 v = *reinterpret_cast<const uint4*>(
            P + (size_t)s * pstride + (size_t)(r0 + m) * ld + k0 + kq);
        *reinterpret_cast<uint4*>(&S[s][m][kq]) = v;        // 80B row pitch: 16B-aligned
    }
}
__device__ __forceinline__ void pstage_KM(const u16* __restrict__ P, size_t pstride, int ld,
                                          int r0, int k0, int tid, u16 S[2][64][BKP]) {
    int k = tid >> 3, mq = (tid & 7) << 3;
#pragma unroll
    for (int s = 0; s < 2; ++s) {
        const uint4 v = *reinterpret_cast<const uint4*>(
            P + (size_t)s * pstride + (size_t)(k0 + k) * ld + r0 + mq);
        const u16* pv = reinterpret_cast<const u16*>(&v);
#pragma unroll
        for (int c = 0; c < 8; ++c) S[s][mq + c][k] = pv[c];
    }
}

// ============ 4-tier f16x2 MFMA core, 32x32x16 shape (64x64 tile, BK=32) ======
// One wave = one 32x32 output frag; 8 MFMA/step (vs 16 of 16x16x32): -17%
// MFMA cycles, half the issue slots -> more room for the co-issued promote.
// tiers: H=a0b0; M=(a0b1+a1b0) [x2^-12]; L=a1b1 [x2^-24].
// H promoted to fp64 EVERY step, unconditionally — round-8-proven cadence
// (r7 conditional / r9 unroll both regressed; do not restructure).
// A/B layout: m(or n)=lane&31, k=(lane>>5)*8+j. C/D [m74/m101-verified]:
// row=(r&3)+8*(r>>2)+4*(lane>>5), col=lane&31.
template<bool AKM, bool BKM>
__device__ __forceinline__ void gemm_core(const u16* __restrict__ Ap, size_t Aps, int lda,
                                          const u16* __restrict__ Bp, size_t Bps, int ldb,
                                          int K, int m0, int n0, int tid,
                                          double outv[16]) {
    __shared__ u16 SA[2][64][BKP], SB[2][64][BKP];
    f32x16 accH, accM, accL;
#pragma unroll
    for (int r = 0; r < 16; ++r) { accH[r] = 0.f; accM[r] = 0.f; accL[r] = 0.f; }
    double accD[16] = {};
    int lane = tid & 63, w = tid >> 6;
    int wm = (w & 1) << 5, wn = (w >> 1) << 5;
    int fr = lane & 31, ko = (lane >> 5) << 3;

    int nstep = K >> 5;
    for (int s = 0; s < nstep; ++s) {
        int k0 = s << 5;
        if (AKM) pstage_KM(Ap, Aps, lda, m0, k0, tid, SA); else pstage_MK(Ap, Aps, lda, m0, k0, tid, SA);
        if (BKM) pstage_KM(Bp, Bps, ldb, n0, k0, tid, SB); else pstage_MK(Bp, Bps, ldb, n0, k0, tid, SB);
        __syncthreads();
        half8 a[2][2], b[2][2];                 // [plane][khalf]
#pragma unroll
        for (int kh = 0; kh < 2; ++kh)
#pragma unroll
            for (int sp = 0; sp < 2; ++sp) {
                a[sp][kh] = *reinterpret_cast<const half8*>(&SA[sp][wm + fr][kh * 16 + ko]);
                b[sp][kh] = *reinterpret_cast<const half8*>(&SB[sp][wn + fr][kh * 16 + ko]);
            }
#pragma unroll
        for (int kh = 0; kh < 2; ++kh) {
            accH = __builtin_amdgcn_mfma_f32_32x32x16_f16(a[0][kh], b[0][kh], accH, 0, 0, 0);
            accM = __builtin_amdgcn_mfma_f32_32x32x16_f16(a[0][kh], b[1][kh], accM, 0, 0, 0);
            accM = __builtin_amdgcn_mfma_f32_32x32x16_f16(a[1][kh], b[0][kh], accM, 0, 0, 0);
            accL = __builtin_amdgcn_mfma_f32_32x32x16_f16(a[1][kh], b[1][kh], accL, 0, 0, 0);
        }
        __syncthreads();
#pragma unroll
        for (int r = 0; r < 16; ++r) { accD[r] += (double)accH[r]; accH[r] = 0.f; }
    }
    const double S1 = 1.0 / 4096.0, S2 = 1.0 / 16777216.0;
#pragma unroll
    for (int r = 0; r < 16; ++r)
        outv[r] = accD[r] + (double)accM[r] * S1 + (double)accL[r] * S2;
}

// ============ prep: RoPE trig table + input f16x2 split (merged launch) =======
__global__ __launch_bounds__(256) void k_prep(const float* __restrict__ x,
                                              const float* __restrict__ Wq,
                                              const float* __restrict__ Wk,
                                              u16* __restrict__ xP,
                                              u16* __restrict__ WP,
                                              double* __restrict__ tg) {
    int bx = blockIdx.x;
    if (bx < L_) {
        int l = bx, j = threadIdx.x;
        double e = (double)j * (1.0 / 256.0);
        double inv = pow(10000.0, -e);
        double ang = (double)l * inv;
        tg[(size_t)l * 512 + j] = cos(ang);
        tg[(size_t)l * 512 + 256 + j] = sin(ang);
        return;
    }
    size_t gid = (size_t)(bx - L_) * 256 + threadIdx.x;
    const size_t XH = X_N / 2, WH = W_N / 2;
    const float* src; u16* dst; size_t pn, off;
    if (gid < XH)            { src = x  + 2 * gid;              dst = xP;            pn = X_N; off = 2 * gid; }
    else if (gid < XH + WH)  { size_t g = gid - XH;      src = Wq + 2 * g; dst = WP;            pn = W_N; off = 2 * g; }
    else                     { size_t g = gid - XH - WH; src = Wk + 2 * g; dst = WP + 2 * W_N;  pn = W_N; off = 2 * g; }
    float2 v = *reinterpret_cast<const float2*>(src);
    u16 a0, a1, b0, b1;
    split2(v.x, a0, a1);
    split2(v.y, b0, b1);
    *reinterpret_cast<unsigned*>(dst + off)      = (unsigned)a0 | ((unsigned)b0 << 16);
    *reinterpret_cast<unsigned*>(dst + pn + off) = (unsigned)a1 | ((unsigned)b1 << 16);
}

// ============ k_proj: plane GEMM ==============================================
__global__ __launch_bounds__(256) void k_proj(const u16* __restrict__ xP,
                                              const u16* __restrict__ WP,
                                              float* __restrict__ qraw,
                                              float* __restrict__ kraw) {
    int z = blockIdx.z;
    float* out = z ? kraw : qraw;
    const u16* Bp = WP + (size_t)z * 2 * W_N;
    int m0 = blockIdx.y * 64, n0 = blockIdx.x * 64;
    double ov[16];
    gemm_core<false, false>(xP, X_N, E_, Bp, W_N, E_, E_, m0, n0, threadIdx.x, ov);
    int lane = threadIdx.x & 63, w = threadIdx.x >> 6;
    int wm = (w & 1) << 5, wn = (w >> 1) << 5;
    int col = n0 + wn + (lane & 31);
    int rofs = (lane >> 5) << 2;
#pragma unroll
    for (int r = 0; r < 16; ++r) {
        int row = m0 + wm + (r & 3) + ((r >> 2) << 3) + rofs;
        out[(size_t)row * D_ + col] = (float)ov[r];
    }
}

// ============ LayerNorm + RoPE (fp64) -> f16x2 planes =========================
__global__ __launch_bounds__(128) void k_lnrope(const float* __restrict__ qraw,
                                                const float* __restrict__ kraw,
                                                const double* __restrict__ tg,
                                                const float* __restrict__ qg, const float* __restrict__ qb,
                                                const float* __restrict__ kg, const float* __restrict__ kb,
                                                u16* __restrict__ qP, u16* __restrict__ kP) {
    int row = blockIdx.x;           // b*2048 + l
    int l = row & (L_ - 1);
    int tid = threadIdx.x;
    __shared__ double nrow[D_];
    __shared__ double red[4];
    __shared__ double cs_[256], sn_[256];
    for (int j = tid; j < 256; j += 128) {
        cs_[j] = tg[(size_t)l * 512 + j];
        sn_[j] = tg[(size_t)l * 512 + 256 + j];
    }
    __syncthreads();
    for (int pass = 0; pass < 2; ++pass) {
        const float* rp = (pass ? kraw : qraw) + (size_t)row * D_;
        const float* g  = pass ? kg : qg;
        const float* bt = pass ? kb : qb;
        u16* P = pass ? kP : qP;
        float4 v = reinterpret_cast<const float4*>(rp)[tid];
        double vv[4] = {(double)v.x, (double)v.y, (double)v.z, (double)v.w};
        double s = vv[0] + vv[1] + vv[2] + vv[3];
        double s2 = vv[0]*vv[0] + vv[1]*vv[1] + vv[2]*vv[2] + vv[3]*vv[3];
        for (int off = 32; off; off >>= 1) { s += __shfl_xor(s, off); s2 += __shfl_xor(s2, off); }
        int wv = tid >> 6;
        if ((tid & 63) == 0) { red[wv * 2] = s; red[wv * 2 + 1] = s2; }
        __syncthreads();
        double mu  = (red[0] + red[2]) * (1.0 / D_);
        double var = (red[1] + red[3]) * (1.0 / D_) - mu * mu;
        double rs = rsqrt(var + 1e-5);
        int d0 = tid * 4;
        double o[4];
#pragma unroll
        for (int c = 0; c < 4; ++c) {
            int d = d0 + c;
            o[c] = (vv[c] - mu) * rs * (double)g[d] + (double)bt[d];
        }
        __syncthreads();
#pragma unroll
        for (int c = 0; c < 4; ++c) nrow[d0 + c] = o[c];
        __syncthreads();
        u16 h[2][4];
#pragma unroll
        for (int c = 0; c < 4; ++c) {
            int d = d0 + c;
            double rot = (d < 256) ? -nrow[d + 256] : nrow[d - 256];
            float ov = (float)(nrow[d] * cs_[d & 255] + rot * sn_[d & 255]);
            split2(ov, h[0][c], h[1][c]);
        }
        size_t off = (size_t)row * D_ + d0;
#pragma unroll
        for (int sp = 0; sp < 2; ++sp)
            *reinterpret_cast<ushort4*>(P + sp * QK_N + off) = make_ushort4(h[sp][0], h[sp][1], h[sp][2], h[sp][3]);
        __syncthreads();
    }
}

// ============ Gram split-K=2: planes -> fp32 partials =========================
__global__ __launch_bounds__(256) void k_gram(const u16* __restrict__ qP,
                                              const u16* __restrict__ kP,
                                              float* __restrict__ Gpart) {
    int zz = blockIdx.z, half = zz & 1, z = zz >> 1;
    int b = z / 3, m = z % 3;
    const u16* A  = ((m == 2) ? qP : kP) + (size_t)b * L_ * D_ + (size_t)half * (L_ / 2) * D_;
    const u16* Bp = ((m == 0) ? kP : qP) + (size_t)b * L_ * D_ + (size_t)half * (L_ / 2) * D_;
    int m0 = blockIdx.y * 64, n0 = blockIdx.x * 64;
    double ov[16];
    gemm_core<true, true>(A, QK_N, D_, Bp, QK_N, D_, L_ / 2, m0, n0, threadIdx.x, ov);
    float* Gg = Gpart + (size_t)half * G_N + (size_t)z * G1_N;
    int lane = threadIdx.x & 63, w = threadIdx.x >> 6;
    int wm = (w & 1) << 5, wn = (w >> 1) << 5;
    int col = n0 + wn + (lane & 31);
    int rofs = (lane >> 5) << 2;
#pragma unroll
    for (int r = 0; r < 16; ++r) {
        int row = m0 + wm + (r & 3) + ((r >> 2) << 3) + rofs;
        Gg[(size_t)row * 512 + col] = (float)ov[r];
    }
}

// ============ sum partials + TRANSPOSE + split into G^T planes ================
__global__ __launch_bounds__(256) void k_gsplitT(const float* __restrict__ Gpart,
                                                 u16* __restrict__ GPT) {
    __shared__ float T[64][65];
    int z = blockIdx.z, d0 = blockIdx.y * 64, e0 = blockIdx.x * 64;
    const float* Ga = Gpart + (size_t)z * G1_N;
    const float* Gb = Ga + G_N;
    int tid = threadIdx.x;
#pragma unroll
    for (int i = 0; i < 16; ++i) {
        int idx = tid + i * 256;
        int r = idx >> 6, c = idx & 63;
        size_t o = (size_t)(d0 + r) * 512 + e0 + c;
        T[r][c] = Ga[o] + Gb[o];
    }
    __syncthreads();
    u16* Gz = GPT + (size_t)z * G1_N;
#pragma unroll
    for (int i = 0; i < 16; ++i) {
        int idx = tid + i * 256;
        int er = idx >> 6, dc = idx & 63;
        u16 h0, h1; split2(T[dc][er], h0, h1);
        size_t o = (size_t)(e0 + er) * 512 + d0 + dc;
        Gz[o] = h0; Gz[G_N + o] = h1;
    }
}

// ============ U = {q,q,k} @ G : planes -> U planes ============================
__global__ __launch_bounds__(256) void k_u(const u16* __restrict__ qP,
                                           const u16* __restrict__ kP,
                                           const u16* __restrict__ GPT,
                                           u16* __restrict__ UP) {
    int z = blockIdx.z, b = z / 3, m = z % 3;
    const u16* A  = ((m == 2) ? kP : qP) + (size_t)b * L_ * D_;
    const u16* Bp = GPT + (size_t)z * G1_N;
    int m0 = blockIdx.y * 64, n0 = blockIdx.x * 64;
    double ov[16];
    gemm_core<false, false>(A, QK_N, D_, Bp, G_N, 512, D_, m0, n0, threadIdx.x, ov);
    int lane = threadIdx.x & 63, w = threadIdx.x >> 6;
    int wm = (w & 1) << 5, wn = (w >> 1) << 5;
    int col = n0 + wn + (lane & 31);
    int rofs = (lane >> 5) << 2;
#pragma unroll
    for (int r = 0; r < 16; ++r) {
        int row = m0 + wm + (r & 3) + ((r >> 2) << 3) + rofs;
        size_t off = (size_t)z * ((size_t)L_ * D_) + (size_t)row * D_ + col;
        u16 h0, h1; split2((float)ov[r], h0, h1);
        UP[off] = h0; UP[U_N + off] = h1;
    }
}

// ============ scores = U @ {q,k,k}^T : planes -> out slots 1..3 ===============
__global__ __launch_bounds__(256) void k_scores(const u16* __restrict__ qP,
                                                const u16* __restrict__ kP,
                                                const u16* __restrict__ UP,
                                                float* __restrict__ out) {
    int z = blockIdx.z, b = z / 3, m = z % 3;
    const u16* A  = UP + (size_t)z * ((size_t)L_ * D_);
    const u16* Bp = ((m == 0) ? qP : kP) + (size_t)b * L_ * D_;
    int m0 = blockIdx.y * 64, n0 = blockIdx.x * 64;
    double ov[16];
    gemm_core<false, false>(A, U_N, D_, Bp, QK_N, D_, D_, m0, n0, threadIdx.x, ov);
    float* Co = out + (size_t)(1 + m) * SLOT + (size_t)b * LL;
    int lane = threadIdx.x & 63, w = threadIdx.x >> 6;
    int wm = (w & 1) << 5, wn = (w >> 1) << 5;
    int col = n0 + wn + (lane & 31);
    int rofs = (lane >> 5) << 2;
#pragma unroll
    for (int r = 0; r < 16; ++r) {
        int row = m0 + wm + (r & 3) + ((r >> 2) << 3) + rofs;
        Co[(size_t)row * L_ + col] = (float)ov[r];
    }
}

// ============ entmax-1.5 (slots 1-3): fp32, 9 bisect + 3 Newton ===============
__global__ __launch_bounds__(256) void k_entmax(float* __restrict__ base, int nrows,
                                                const float* __restrict__ wC,
                                                const float* __restrict__ wF,
                                                const float* __restrict__ wS) {
    int tid = threadIdx.x;
    int lane = tid & 63;
    int r = blockIdx.x * 4 + (tid >> 6);
    if (r >= nrows) return;
    int m = r >> 12;                 // 4096 rows per matrix
    const float* wp = (m == 0) ? wC : (m == 1) ? wF : wS;
    float hw = (float)(1.0 / (1.0 + exp(-(double)wp[0])));   // 0.5 * w
    float* row = base + (size_t)r * L_;
    float v[32];
    float mx = -3.4e38f;
#pragma unroll
    for (int j = 0; j < 32; ++j) {
        v[j] = row[lane + (j << 6)];
        mx = fmaxf(mx, v[j]);
    }
    for (int off = 32; off; off >>= 1) mx = fmaxf(mx, __shfl_xor(mx, off));
    float z[32];
#pragma unroll
    for (int j = 0; j < 32; ++j) z[j] = hw * (v[j] - mx);
    float lo = -1.0f, hi = 0.0f;
    for (int it = 0; it < 9; ++it) {
        float tau = 0.5f * (lo + hi);
        float ssum = 0.0f;
#pragma unroll
        for (int j = 0; j < 32; ++j) {
            float t = fmaxf(z[j] - tau, 0.0f);
            ssum = fmaf(t, t, ssum);
        }
        for (int off = 32; off; off >>= 1) ssum += __shfl_xor(ssum, off);
        if (ssum >= 1.0f) lo = tau; else hi = tau;
    }
    float tau = lo;   // f(lo) >= 1; Newton on convex f approaches root from left
    for (int it = 0; it < 3; ++it) {
        float s1 = 0.0f, s2 = 0.0f;
#pragma unroll
        for (int j = 0; j < 32; ++j) {
            float t = fmaxf(z[j] - tau, 0.0f);
            s1 += t;
            s2 = fmaf(t, t, s2);
        }
        for (int off = 32; off; off >>= 1) { s1 += __shfl_xor(s1, off); s2 += __shfl_xor(s2, off); }
        float denom = 2.0f * s1;
        if (denom > 1e-30f) tau += fmaxf((s2 - 1.0f) / denom, 0.0f);
    }
#pragma unroll
    for (int j = 0; j < 32; ++j) {
        float t = fmaxf(z[j] - tau, 0.0f);
        row[lane + (j << 6)] = fminf(t * t, 1.0f - 1e-6f);
    }
}

// ============ column sums: partials (deterministic, parallel) =================
__global__ __launch_bounds__(256) void k_colsum(const float* __restrict__ out,
                                                double* __restrict__ part) {
    int bz = blockIdx.z, which = bz >> 1, b = bz & 1;
    const float* mat = out + (size_t)(which ? 3 : 1) * SLOT + (size_t)b * LL;
    int j = blockIdx.x * 256 + threadIdx.x;
    int r0 = blockIdx.y * 128;
    double s = 0.0;
#pragma unroll 8
    for (int r = 0; r < 128; ++r) s += (double)mat[(size_t)(r0 + r) * L_ + j];
    part[((size_t)bz * 16 + blockIdx.y) * L_ + j] = s;
}

__global__ __launch_bounds__(256) void k_colred(const double* __restrict__ part,
                                                double* __restrict__ csC,
                                                double* __restrict__ csS) {
    int g = blockIdx.x * 256 + threadIdx.x;   // 0..8191 = bz*2048 + j
    int bz = g >> 11, j = g & (L_ - 1);
    int which = bz >> 1, b = bz & 1;
    double s = 0.0;
#pragma unroll
    for (int c = 0; c < 16; ++c) s += part[((size_t)bz * 16 + c) * L_ + j];
    (which ? csS : csC)[b * L_ + j] = s;
}

// ============ fused finalize + entmax(H): one block per row ===================
__global__ __launch_bounds__(256) void k_fin2(float* __restrict__ out,
                                              const double* __restrict__ csC,
                                              const double* __restrict__ csS) {
    int row = blockIdx.x;               // b*2048 + i
    int i = row & (L_ - 1), b = row >> 11;
    size_t ro = (size_t)row * L_;
    float* H  = out + ro;
    float* pC = out + SLOT + ro;
    float* pF = out + 2 * SLOT + ro;
    float* pS = out + 3 * SLOT + ro;
    const double* cc = csC + b * L_;
    const double* cs = csS + b * L_;
    int tid = threadIdx.x, lane = tid & 63, wv = tid >> 6;
    __shared__ float red[4], red2[4];
    const double A1 = 1.0 - 2e-6;
    float h[8];
    float mx = -3.4e38f;
#pragma unroll
    for (int c = 0; c < 8; ++c) {
        int j = (c << 8) + tid;
        double cv = (double)pC[j] * rsqrt(cc[j] + 1e-6);
        double fv = (double)pF[j];
        double sv = (double)pS[j] * rsqrt(cs[j] + 1e-6);
        cv = fmax(A1 * cv + 1e-6, 1e-6);
        fv = fmax(A1 * fv + 1e-6, 1e-6);
        sv = fmax(A1 * sv + 1e-6, 1e-6);
        pC[j] = (float)cv; pF[j] = (float)fv; pS[j] = (float)sv;
        h[c] = (j == i) ? -1e9f : logf((float)(cv * fv * sv)) * (1.0f / 3.0f);
        mx = fmaxf(mx, h[c]);
    }
    for (int off = 32; off; off >>= 1) mx = fmaxf(mx, __shfl_xor(mx, off));
    if (lane == 0) red[wv] = mx;
    __syncthreads();
    mx = fmaxf(fmaxf(red[0], red[1]), fmaxf(red[2], red[3]));
    __syncthreads();
    float z[8];
#pragma unroll
    for (int c = 0; c < 8; ++c) z[c] = 0.5f * (h[c] - mx);
    float lo = -1.0f, hi = 0.0f;
    for (int it = 0; it < 9; ++it) {
        float tau = 0.5f * (lo + hi);
        float ssum = 0.0f;
#pragma unroll
        for (int c = 0; c < 8; ++c) {
            float t = fmaxf(z[c] - tau, 0.0f);
            ssum = fmaf(t, t, ssum);
        }
        for (int off = 32; off; off >>= 1) ssum += __shfl_xor(ssum, off);
        if (lane == 0) red[wv] = ssum;
        __syncthreads();
        ssum = red[0] + red[1] + red[2] + red[3];
        __syncthreads();
        if (ssum >= 1.0f) lo = tau; else hi = tau;
    }
    float tau = lo;
    for (int it = 0; it < 3; ++it) {
        float s1 = 0.0f, s2 = 0.0f;
#pragma unroll
        for (int c = 0; c < 8; ++c) {
            float t = fmaxf(z[c] - tau, 0.0f);
            s1 += t;
            s2 = fmaf(t, t, s2);
        }
        for (int off = 32; off; off >>= 1) { s1 += __shfl_xor(s1, off); s2 += __shfl_xor(s2, off); }
        if (lane == 0) { red[wv] = s1; red2[wv] = s2; }
        __syncthreads();
        s1 = red[0] + red[1] + red[2] + red[3];
        s2 = red2[0] + red2[1] + red2[2] + red2[3];
        __syncthreads();
        float denom = 2.0f * s1;
        if (denom > 1e-30f) tau += fmaxf((s2 - 1.0f) / denom, 0.0f);
    }
#pragma unroll
    for (int c = 0; c < 8; ++c) {
        float t = fmaxf(z[c] - tau, 0.0f);
        H[(c << 8) + tid] = t * t;
    }
}

// ============ launch ==========================================================
extern "C" void kernel_launch(void* const* d_in, const int* in_sizes, int n_in,
                              void* d_out, int out_size, void* d_ws, size_t ws_size,
                              hipStream_t stream) {
    const float* x  = (const float*)d_in[0];
    const float* Wq = (const float*)d_in[1];
    const float* Wk = (const float*)d_in[2];
    const float* qg = (const float*)d_in[3];
    const float* qb = (const float*)d_in[4];
    const float* kg = (const float*)d_in[5];
    const float* kb = (const float*)d_in[6];
    const float* wC = (const float*)d_in[7];
    const float* wF = (const float*)d_in[8];
    const float* wS = (const float*)d_in[9];
    float* out = (float*)d_out;

    // workspace: region boundaries identical to proven round-11/12 layout.
    char* wsb = (char*)d_ws;
    u16*    UP   = (u16*)wsb;
    float*  qraw = (float*)wsb;
    float*  kraw = qraw + QK_N;
    float*  Gpart = (float*)(wsb + 2 * QK_N * sizeof(float));
    wsb += 3 * U_N * sizeof(u16);                               // 37.75 MB region
    u16*    qP    = (u16*)wsb;
    u16*    xP    = (u16*)wsb;   wsb += 3 * QK_N * sizeof(u16); // 12.6 MB region
    u16*    kP    = (u16*)wsb;   wsb += 3 * QK_N * sizeof(u16); // 12.6 MB region
    u16*    GPT   = (u16*)wsb;
    u16*    WP    = (u16*)wsb;   wsb += 3 * G_N * sizeof(u16);  // 9.4 MB region
    double* tg    = (double*)wsb;                                // 8.4 MB region
    double* part  = tg;                                          // 1 MB   (alias)
    double* csC   = tg + (size_t)4 * 16 * L_;                    // 32 KB  (alias)
    double* csS   = csC + (size_t)B_ * L_;                       // 32 KB  (alias)

    k_prep    <<<dim3(L_ + 7680), 256, 0, stream>>>(x, Wq, Wk, xP, WP, tg);
    k_proj    <<<dim3(8, 64, 2),  256, 0, stream>>>(xP, WP, qraw, kraw);
    k_lnrope  <<<dim3(B_ * L_),   128, 0, stream>>>(qraw, kraw, tg, qg, qb, kg, kb, qP, kP);
    k_gram    <<<dim3(8, 8, 12),  256, 0, stream>>>(qP, kP, Gpart);
    k_gsplitT <<<dim3(8, 8, 6),   256, 0, stream>>>(Gpart, GPT);
    k_u       <<<dim3(8, 32, 6),  256, 0, stream>>>(qP, kP, GPT, UP);
    k_scores  <<<dim3(32, 32, 6), 256, 0, stream>>>(qP, kP, UP, out);
    k_entmax  <<<dim3(3072),      256, 0, stream>>>(out + SLOT, 3 * B_ * L_, wC, wF, wS);
    k_colsum  <<<dim3(8, 16, 4),  256, 0, stream>>>(out, part);
    k_colred  <<<dim3(32),        256, 0, stream>>>(part, csC, csS);
    k_fin2    <<<dim3(B_ * L_),   256, 0, stream>>>(out, csC, csS);
}

// Round 14
// 575.841 us; speedup vs baseline: 1.1318x; 1.1318x over previous
//
#include <hip/hip_runtime.h>
#include <cstddef>
#include <math.h>

// ---------------- problem constants ----------------
#define B_   2
#define L_   2048
#define D_   512
#define E_   768
static const size_t LL   = (size_t)L_ * L_;
static const size_t SLOT = (size_t)B_ * LL;

#define QK_N  ((size_t)B_ * L_ * D_)       // 2097152
#define G1_N  ((size_t)512 * 512)          // 262144
#define G_N   ((size_t)6 * G1_N)           // 1572864
#define U_N   ((size_t)6 * L_ * D_)        // 6291456
#define X_N   ((size_t)4096 * 768)         // 3145728
#define W_N   ((size_t)512 * 768)          // 393216

typedef unsigned short u16;
typedef __attribute__((ext_vector_type(8))) _Float16 half8;  // 8 f16 (4 VGPR)
typedef __attribute__((ext_vector_type(4))) float f32x4;

// ---------------- f16x2 split of fp32, scaled residual ------------------------
// f = h0 + h1/4096 + r2, |r2| <= |f|*2^-24. Round-14: the a1*b1 (2^-24) product
// tier is DROPPED — error budget: scores err ~4e-3 -> p err <= ~6e-3 vs 2e-2.
__device__ __forceinline__ void split2(float f, u16& h0, u16& h1) {
    _Float16 a = (_Float16)f;
    _Float16 b = (_Float16)((f - (float)a) * 4096.0f);
    h0 = __builtin_bit_cast(u16, a);
    h1 = __builtin_bit_cast(u16, b);
}

#define BKP 40   // LDS row pitch in u16 (pad: frag reads ~2-way banks)

// ============ plane-based stagers (16B global loads, 2 planes) ================
__device__ __forceinline__ void pstage_MK(const u16* __restrict__ P, size_t pstride, int ld,
                                          int r0, int k0, int tid, u16 S[2][64][BKP]) {
    int m = tid >> 2, kq = (tid & 3) << 3;                  // 8 u16 = 16B per thread
#pragma unroll
    for (int s = 0; s < 2; ++s) {
        const uint4 v = *reinterpret_cast<const uint4*>(
            P + (size_t)s * pstride + (size_t)(r0 + m) * ld + k0 + kq);
        *reinterpret_cast<uint4*>(&S[s][m][kq]) = v;        // 80B row pitch: 16B-aligned
    }
}
__device__ __forceinline__ void pstage_KM(const u16* __restrict__ P, size_t pstride, int ld,
                                          int r0, int k0, int tid, u16 S[2][64][BKP]) {
    int k = tid >> 3, mq = (tid & 7) << 3;
#pragma unroll
    for (int s = 0; s < 2; ++s) {
        const uint4 v = *reinterpret_cast<const uint4*>(
            P + (size_t)s * pstride + (size_t)(k0 + k) * ld + r0 + mq);
        const u16* pv = reinterpret_cast<const u16*>(&v);
#pragma unroll
        for (int c = 0; c < 8; ++c) S[s][mq + c][k] = pv[c];
    }
}

// ============ 3-tier f16x2 MFMA core, 16x16x32 shape (64x64 tile, BK=32) ======
// ROUND-12-PROVEN STRUCTURE (round-13's 32x32 shape regressed: only 3 indep
// MFMA chains -> latency-bound; this core has 8 chains of short 4.85-cyc ops).
// tiers: H=a0b0 (fp64-promoted EVERY step — r7/r9 cadence changes regressed);
//        M=(a0b1+a1b0) [x2^-12]. L tier dropped (round 14).
template<bool AKM, bool BKM>
__device__ __forceinline__ void gemm_core(const u16* __restrict__ Ap, size_t Aps, int lda,
                                          const u16* __restrict__ Bp, size_t Bps, int ldb,
                                          int K, int m0, int n0, int tid,
                                          double outv[2][2][4]) {
    __shared__ u16 SA[2][64][BKP], SB[2][64][BKP];
    f32x4 accH[2][2], accM[2][2];
#pragma unroll
    for (int i = 0; i < 2; ++i)
#pragma unroll
        for (int j = 0; j < 2; ++j) {
            accH[i][j] = (f32x4){0.f, 0.f, 0.f, 0.f};
            accM[i][j] = (f32x4){0.f, 0.f, 0.f, 0.f};
        }
    double accD[2][2][4] = {};
    int lane = tid & 63, w = tid >> 6;
    int wm = (w & 1) << 5, wn = (w >> 1) << 5;
    int fr = lane & 15, ko = (lane >> 4) << 3;

    int nstep = K >> 5;
    for (int s = 0; s < nstep; ++s) {
        int k0 = s << 5;
        if (AKM) pstage_KM(Ap, Aps, lda, m0, k0, tid, SA); else pstage_MK(Ap, Aps, lda, m0, k0, tid, SA);
        if (BKM) pstage_KM(Bp, Bps, ldb, n0, k0, tid, SB); else pstage_MK(Bp, Bps, ldb, n0, k0, tid, SB);
        __syncthreads();
        half8 a[2][2], b[2][2];
#pragma unroll
        for (int f = 0; f < 2; ++f)
#pragma unroll
            for (int sp = 0; sp < 2; ++sp) {
                a[f][sp] = *reinterpret_cast<const half8*>(&SA[sp][wm + f * 16 + fr][ko]);
                b[f][sp] = *reinterpret_cast<const half8*>(&SB[sp][wn + f * 16 + fr][ko]);
            }
#pragma unroll
        for (int fi = 0; fi < 2; ++fi)
#pragma unroll
            for (int fj = 0; fj < 2; ++fj) {
                accH[fi][fj] = __builtin_amdgcn_mfma_f32_16x16x32_f16(a[fi][0], b[fj][0], accH[fi][fj], 0, 0, 0);
                accM[fi][fj] = __builtin_amdgcn_mfma_f32_16x16x32_f16(a[fi][0], b[fj][1], accM[fi][fj], 0, 0, 0);
                accM[fi][fj] = __builtin_amdgcn_mfma_f32_16x16x32_f16(a[fi][1], b[fj][0], accM[fi][fj], 0, 0, 0);
            }
        __syncthreads();
#pragma unroll
        for (int fi = 0; fi < 2; ++fi)
#pragma unroll
            for (int fj = 0; fj < 2; ++fj) {
#pragma unroll
                for (int r = 0; r < 4; ++r) accD[fi][fj][r] += (double)accH[fi][fj][r];
                accH[fi][fj] = (f32x4){0.f, 0.f, 0.f, 0.f};
            }
    }
    const double S1 = 1.0 / 4096.0;
#pragma unroll
    for (int fi = 0; fi < 2; ++fi)
#pragma unroll
        for (int fj = 0; fj < 2; ++fj)
#pragma unroll
            for (int r = 0; r < 4; ++r)
                outv[fi][fj][r] = accD[fi][fj][r] + (double)accM[fi][fj][r] * S1;
}

// ============ prep: RoPE trig table + input f16x2 split (merged launch) =======
__global__ __launch_bounds__(256) void k_prep(const float* __restrict__ x,
                                              const float* __restrict__ Wq,
                                              const float* __restrict__ Wk,
                                              u16* __restrict__ xP,
                                              u16* __restrict__ WP,
                                              double* __restrict__ tg) {
    int bx = blockIdx.x;
    if (bx < L_) {
        int l = bx, j = threadIdx.x;
        double e = (double)j * (1.0 / 256.0);
        double inv = pow(10000.0, -e);
        double ang = (double)l * inv;
        tg[(size_t)l * 512 + j] = cos(ang);
        tg[(size_t)l * 512 + 256 + j] = sin(ang);
        return;
    }
    size_t gid = (size_t)(bx - L_) * 256 + threadIdx.x;
    const size_t XH = X_N / 2, WH = W_N / 2;
    const float* src; u16* dst; size_t pn, off;
    if (gid < XH)            { src = x  + 2 * gid;              dst = xP;            pn = X_N; off = 2 * gid; }
    else if (gid < XH + WH)  { size_t g = gid - XH;      src = Wq + 2 * g; dst = WP;            pn = W_N; off = 2 * g; }
    else                     { size_t g = gid - XH - WH; src = Wk + 2 * g; dst = WP + 2 * W_N;  pn = W_N; off = 2 * g; }
    float2 v = *reinterpret_cast<const float2*>(src);
    u16 a0, a1, b0, b1;
    split2(v.x, a0, a1);
    split2(v.y, b0, b1);
    *reinterpret_cast<unsigned*>(dst + off)      = (unsigned)a0 | ((unsigned)b0 << 16);
    *reinterpret_cast<unsigned*>(dst + pn + off) = (unsigned)a1 | ((unsigned)b1 << 16);
}

// ============ k_proj: plane GEMM ==============================================
__global__ __launch_bounds__(256) void k_proj(const u16* __restrict__ xP,
                                              const u16* __restrict__ WP,
                                              float* __restrict__ qraw,
                                              float* __restrict__ kraw) {
    int z = blockIdx.z;
    float* out = z ? kraw : qraw;
    const u16* Bp = WP + (size_t)z * 2 * W_N;
    int m0 = blockIdx.y * 64, n0 = blockIdx.x * 64;
    double ov[2][2][4];
    gemm_core<false, false>(xP, X_N, E_, Bp, W_N, E_, E_, m0, n0, threadIdx.x, ov);
    int lane = threadIdx.x & 63, w = threadIdx.x >> 6;
    int wm = (w & 1) << 5, wn = (w >> 1) << 5;
    int col = lane & 15, rbase = (lane >> 4) << 2;
#pragma unroll
    for (int fi = 0; fi < 2; ++fi)
#pragma unroll
        for (int fj = 0; fj < 2; ++fj)
#pragma unroll
            for (int r = 0; r < 4; ++r) {
                int mm = m0 + wm + fi * 16 + rbase + r;
                int nn = n0 + wn + fj * 16 + col;
                out[(size_t)mm * D_ + nn] = (float)ov[fi][fj][r];
            }
}

// ============ LayerNorm + RoPE (fp64) -> f16x2 planes =========================
__global__ __launch_bounds__(128) void k_lnrope(const float* __restrict__ qraw,
                                                const float* __restrict__ kraw,
                                                const double* __restrict__ tg,
                                                const float* __restrict__ qg, const float* __restrict__ qb,
                                                const float* __restrict__ kg, const float* __restrict__ kb,
                                                u16* __restrict__ qP, u16* __restrict__ kP) {
    int row = blockIdx.x;           // b*2048 + l
    int l = row & (L_ - 1);
    int tid = threadIdx.x;
    __shared__ double nrow[D_];
    __shared__ double red[4];
    __shared__ double cs_[256], sn_[256];
    for (int j = tid; j < 256; j += 128) {
        cs_[j] = tg[(size_t)l * 512 + j];
        sn_[j] = tg[(size_t)l * 512 + 256 + j];
    }
    __syncthreads();
    for (int pass = 0; pass < 2; ++pass) {
        const float* rp = (pass ? kraw : qraw) + (size_t)row * D_;
        const float* g  = pass ? kg : qg;
        const float* bt = pass ? kb : qb;
        u16* P = pass ? kP : qP;
        float4 v = reinterpret_cast<const float4*>(rp)[tid];
        double vv[4] = {(double)v.x, (double)v.y, (double)v.z, (double)v.w};
        double s = vv[0] + vv[1] + vv[2] + vv[3];
        double s2 = vv[0]*vv[0] + vv[1]*vv[1] + vv[2]*vv[2] + vv[3]*vv[3];
        for (int off = 32; off; off >>= 1) { s += __shfl_xor(s, off); s2 += __shfl_xor(s2, off); }
        int wv = tid >> 6;
        if ((tid & 63) == 0) { red[wv * 2] = s; red[wv * 2 + 1] = s2; }
        __syncthreads();
        double mu  = (red[0] + red[2]) * (1.0 / D_);
        double var = (red[1] + red[3]) * (1.0 / D_) - mu * mu;
        double rs = rsqrt(var + 1e-5);
        int d0 = tid * 4;
        double o[4];
#pragma unroll
        for (int c = 0; c < 4; ++c) {
            int d = d0 + c;
            o[c] = (vv[c] - mu) * rs * (double)g[d] + (double)bt[d];
        }
        __syncthreads();
#pragma unroll
        for (int c = 0; c < 4; ++c) nrow[d0 + c] = o[c];
        __syncthreads();
        u16 h[2][4];
#pragma unroll
        for (int c = 0; c < 4; ++c) {
            int d = d0 + c;
            double rot = (d < 256) ? -nrow[d + 256] : nrow[d - 256];
            float ov = (float)(nrow[d] * cs_[d & 255] + rot * sn_[d & 255]);
            split2(ov, h[0][c], h[1][c]);
        }
        size_t off = (size_t)row * D_ + d0;
#pragma unroll
        for (int sp = 0; sp < 2; ++sp)
            *reinterpret_cast<ushort4*>(P + sp * QK_N + off) = make_ushort4(h[sp][0], h[sp][1], h[sp][2], h[sp][3]);
        __syncthreads();
    }
}

// ============ Gram split-K=2: planes -> fp32 partials =========================
__global__ __launch_bounds__(256) void k_gram(const u16* __restrict__ qP,
                                              const u16* __restrict__ kP,
                                              float* __restrict__ Gpart) {
    int zz = blockIdx.z, half = zz & 1, z = zz >> 1;
    int b = z / 3, m = z % 3;
    const u16* A  = ((m == 2) ? qP : kP) + (size_t)b * L_ * D_ + (size_t)half * (L_ / 2) * D_;
    const u16* Bp = ((m == 0) ? kP : qP) + (size_t)b * L_ * D_ + (size_t)half * (L_ / 2) * D_;
    int m0 = blockIdx.y * 64, n0 = blockIdx.x * 64;
    double ov[2][2][4];
    gemm_core<true, true>(A, QK_N, D_, Bp, QK_N, D_, L_ / 2, m0, n0, threadIdx.x, ov);
    float* Gg = Gpart + (size_t)half * G_N + (size_t)z * G1_N;
    int lane = threadIdx.x & 63, w = threadIdx.x >> 6;
    int wm = (w & 1) << 5, wn = (w >> 1) << 5;
    int col = lane & 15, rbase = (lane >> 4) << 2;
#pragma unroll
    for (int fi = 0; fi < 2; ++fi)
#pragma unroll
        for (int fj = 0; fj < 2; ++fj)
#pragma unroll
            for (int r = 0; r < 4; ++r) {
                int mm = m0 + wm + fi * 16 + rbase + r;
                int nn = n0 + wn + fj * 16 + col;
                Gg[(size_t)mm * 512 + nn] = (float)ov[fi][fj][r];
            }
}

// ============ sum partials + TRANSPOSE + split into G^T planes ================
__global__ __launch_bounds__(256) void k_gsplitT(const float* __restrict__ Gpart,
                                                 u16* __restrict__ GPT) {
    __shared__ float T[64][65];
    int z = blockIdx.z, d0 = blockIdx.y * 64, e0 = blockIdx.x * 64;
    const float* Ga = Gpart + (size_t)z * G1_N;
    const float* Gb = Ga + G_N;
    int tid = threadIdx.x;
#pragma unroll
    for (int i = 0; i < 16; ++i) {
        int idx = tid + i * 256;
        int r = idx >> 6, c = idx & 63;
        size_t o = (size_t)(d0 + r) * 512 + e0 + c;
        T[r][c] = Ga[o] + Gb[o];
    }
    __syncthreads();
    u16* Gz = GPT + (size_t)z * G1_N;
#pragma unroll
    for (int i = 0; i < 16; ++i) {
        int idx = tid + i * 256;
        int er = idx >> 6, dc = idx & 63;
        u16 h0, h1; split2(T[dc][er], h0, h1);
        size_t o = (size_t)(e0 + er) * 512 + d0 + dc;
        Gz[o] = h0; Gz[G_N + o] = h1;
    }
}

// ============ U = {q,q,k} @ G : planes -> U planes ============================
__global__ __launch_bounds__(256) void k_u(const u16* __restrict__ qP,
                                           const u16* __restrict__ kP,
                                           const u16* __restrict__ GPT,
                                           u16* __restrict__ UP) {
    int z = blockIdx.z, b = z / 3, m = z % 3;
    const u16* A  = ((m == 2) ? kP : qP) + (size_t)b * L_ * D_;
    const u16* Bp = GPT + (size_t)z * G1_N;
    int m0 = blockIdx.y * 64, n0 = blockIdx.x * 64;
    double ov[2][2][4];
    gemm_core<false, false>(A, QK_N, D_, Bp, G_N, 512, D_, m0, n0, threadIdx.x, ov);
    int lane = threadIdx.x & 63, w = threadIdx.x >> 6;
    int wm = (w & 1) << 5, wn = (w >> 1) << 5;
    int col = lane & 15, rbase = (lane >> 4) << 2;
#pragma unroll
    for (int fi = 0; fi < 2; ++fi)
#pragma unroll
        for (int fj = 0; fj < 2; ++fj)
#pragma unroll
            for (int r = 0; r < 4; ++r) {
                float uf = (float)ov[fi][fj][r];
                int mm = m0 + wm + fi * 16 + rbase + r;
                int nn = n0 + wn + fj * 16 + col;
                size_t off = (size_t)z * ((size_t)L_ * D_) + (size_t)mm * D_ + nn;
                u16 h0, h1; split2(uf, h0, h1);
                UP[off] = h0; UP[U_N + off] = h1;
            }
}

// ============ scores = U @ {q,k,k}^T : planes -> out slots 1..3 ===============
__global__ __launch_bounds__(256) void k_scores(const u16* __restrict__ qP,
                                                const u16* __restrict__ kP,
                                                const u16* __restrict__ UP,
                                                float* __restrict__ out) {
    int z = blockIdx.z, b = z / 3, m = z % 3;
    const u16* A  = UP + (size_t)z * ((size_t)L_ * D_);
    const u16* Bp = ((m == 0) ? qP : kP) + (size_t)b * L_ * D_;
    int m0 = blockIdx.y * 64, n0 = blockIdx.x * 64;
    double ov[2][2][4];
    gemm_core<false, false>(A, U_N, D_, Bp, QK_N, D_, D_, m0, n0, threadIdx.x, ov);
    float* Co = out + (size_t)(1 + m) * SLOT + (size_t)b * LL;
    int lane = threadIdx.x & 63, w = threadIdx.x >> 6;
    int wm = (w & 1) << 5, wn = (w >> 1) << 5;
    int col = lane & 15, rbase = (lane >> 4) << 2;
#pragma unroll
    for (int fi = 0; fi < 2; ++fi)
#pragma unroll
        for (int fj = 0; fj < 2; ++fj)
#pragma unroll
            for (int r = 0; r < 4; ++r) {
                int mm = m0 + wm + fi * 16 + rbase + r;
                int nn = n0 + wn + fj * 16 + col;
                Co[(size_t)mm * L_ + nn] = (float)ov[fi][fj][r];
            }
}

// ============ entmax-1.5 (slots 1-3): fp32, 9 bisect + 3 Newton ===============
__global__ __launch_bounds__(256) void k_entmax(float* __restrict__ base, int nrows,
                                                const float* __restrict__ wC,
                                                const float* __restrict__ wF,
                                                const float* __restrict__ wS) {
    int tid = threadIdx.x;
    int lane = tid & 63;
    int r = blockIdx.x * 4 + (tid >> 6);
    if (r >= nrows) return;
    int m = r >> 12;                 // 4096 rows per matrix
    const float* wp = (m == 0) ? wC : (m == 1) ? wF : wS;
    float hw = (float)(1.0 / (1.0 + exp(-(double)wp[0])));   // 0.5 * w
    float* row = base + (size_t)r * L_;
    float v[32];
    float mx = -3.4e38f;
#pragma unroll
    for (int j = 0; j < 32; ++j) {
        v[j] = row[lane + (j << 6)];
        mx = fmaxf(mx, v[j]);
    }
    for (int off = 32; off; off >>= 1) mx = fmaxf(mx, __shfl_xor(mx, off));
    float z[32];
#pragma unroll
    for (int j = 0; j < 32; ++j) z[j] = hw * (v[j] - mx);
    float lo = -1.0f, hi = 0.0f;
    for (int it = 0; it < 9; ++it) {
        float tau = 0.5f * (lo + hi);
        float ssum = 0.0f;
#pragma unroll
        for (int j = 0; j < 32; ++j) {
            float t = fmaxf(z[j] - tau, 0.0f);
            ssum = fmaf(t, t, ssum);
        }
        for (int off = 32; off; off >>= 1) ssum += __shfl_xor(ssum, off);
        if (ssum >= 1.0f) lo = tau; else hi = tau;
    }
    float tau = lo;   // f(lo) >= 1; Newton on convex f approaches root from left
    for (int it = 0; it < 3; ++it) {
        float s1 = 0.0f, s2 = 0.0f;
#pragma unroll
        for (int j = 0; j < 32; ++j) {
            float t = fmaxf(z[j] - tau, 0.0f);
            s1 += t;
            s2 = fmaf(t, t, s2);
        }
        for (int off = 32; off; off >>= 1) { s1 += __shfl_xor(s1, off); s2 += __shfl_xor(s2, off); }
        float denom = 2.0f * s1;
        if (denom > 1e-30f) tau += fmaxf((s2 - 1.0f) / denom, 0.0f);
    }
#pragma unroll
    for (int j = 0; j < 32; ++j) {
        float t = fmaxf(z[j] - tau, 0.0f);
        row[lane + (j << 6)] = fminf(t * t, 1.0f - 1e-6f);
    }
}

// ============ column sums: partials (deterministic, parallel) =================
__global__ __launch_bounds__(256) void k_colsum(const float* __restrict__ out,
                                                double* __restrict__ part) {
    int bz = blockIdx.z, which = bz >> 1, b = bz & 1;
    const float* mat = out + (size_t)(which ? 3 : 1) * SLOT + (size_t)b * LL;
    int j = blockIdx.x * 256 + threadIdx.x;
    int r0 = blockIdx.y * 128;
    double s = 0.0;
#pragma unroll 8
    for (int r = 0; r < 128; ++r) s += (double)mat[(size_t)(r0 + r) * L_ + j];
    part[((size_t)bz * 16 + blockIdx.y) * L_ + j] = s;
}

__global__ __launch_bounds__(256) void k_colred(const double* __restrict__ part,
                                                double* __restrict__ csC,
                                                double* __restrict__ csS) {
    int g = blockIdx.x * 256 + threadIdx.x;   // 0..8191 = bz*2048 + j
    int bz = g >> 11, j = g & (L_ - 1);
    int which = bz >> 1, b = bz & 1;
    double s = 0.0;
#pragma unroll
    for (int c = 0; c < 16; ++c) s += part[((size_t)bz * 16 + c) * L_ + j];
    (which ? csS : csC)[b * L_ + j] = s;
}

// ============ fused finalize + entmax(H): one block per row ===================
__global__ __launch_bounds__(256) void k_fin2(float* __restrict__ out,
                                              const double* __restrict__ csC,
                                              const double* __restrict__ csS) {
    int row = blockIdx.x;               // b*2048 + i
    int i = row & (L_ - 1), b = row >> 11;
    size_t ro = (size_t)row * L_;
    float* H  = out + ro;
    float* pC = out + SLOT + ro;
    float* pF = out + 2 * SLOT + ro;
    float* pS = out + 3 * SLOT + ro;
    const double* cc = csC + b * L_;
    const double* cs = csS + b * L_;
    int tid = threadIdx.x, lane = tid & 63, wv = tid >> 6;
    __shared__ float red[4], red2[4];
    const double A1 = 1.0 - 2e-6;
    float h[8];
    float mx = -3.4e38f;
#pragma unroll
    for (int c = 0; c < 8; ++c) {
        int j = (c << 8) + tid;
        double cv = (double)pC[j] * rsqrt(cc[j] + 1e-6);
        double fv = (double)pF[j];
        double sv = (double)pS[j] * rsqrt(cs[j] + 1e-6);
        cv = fmax(A1 * cv + 1e-6, 1e-6);
        fv = fmax(A1 * fv + 1e-6, 1e-6);
        sv = fmax(A1 * sv + 1e-6, 1e-6);
        pC[j] = (float)cv; pF[j] = (float)fv; pS[j] = (float)sv;
        h[c] = (j == i) ? -1e9f : logf((float)(cv * fv * sv)) * (1.0f / 3.0f);
        mx = fmaxf(mx, h[c]);
    }
    for (int off = 32; off; off >>= 1) mx = fmaxf(mx, __shfl_xor(mx, off));
    if (lane == 0) red[wv] = mx;
    __syncthreads();
    mx = fmaxf(fmaxf(red[0], red[1]), fmaxf(red[2], red[3]));
    __syncthreads();
    float z[8];
#pragma unroll
    for (int c = 0; c < 8; ++c) z[c] = 0.5f * (h[c] - mx);
    float lo = -1.0f, hi = 0.0f;
    for (int it = 0; it < 9; ++it) {
        float tau = 0.5f * (lo + hi);
        float ssum = 0.0f;
#pragma unroll
        for (int c = 0; c < 8; ++c) {
            float t = fmaxf(z[c] - tau, 0.0f);
            ssum = fmaf(t, t, ssum);
        }
        for (int off = 32; off; off >>= 1) ssum += __shfl_xor(ssum, off);
        if (lane == 0) red[wv] = ssum;
        __syncthreads();
        ssum = red[0] + red[1] + red[2] + red[3];
        __syncthreads();
        if (ssum >= 1.0f) lo = tau; else hi = tau;
    }
    float tau = lo;
    for (int it = 0; it < 3; ++it) {
        float s1 = 0.0f, s2 = 0.0f;
#pragma unroll
        for (int c = 0; c < 8; ++c) {
            float t = fmaxf(z[c] - tau, 0.0f);
            s1 += t;
            s2 = fmaf(t, t, s2);
        }
        for (int off = 32; off; off >>= 1) { s1 += __shfl_xor(s1, off); s2 += __shfl_xor(s2, off); }
        if (lane == 0) { red[wv] = s1; red2[wv] = s2; }
        __syncthreads();
        s1 = red[0] + red[1] + red[2] + red[3];
        s2 = red2[0] + red2[1] + red2[2] + red2[3];
        __syncthreads();
        float denom = 2.0f * s1;
        if (denom > 1e-30f) tau += fmaxf((s2 - 1.0f) / denom, 0.0f);
    }
#pragma unroll
    for (int c = 0; c < 8; ++c) {
        float t = fmaxf(z[c] - tau, 0.0f);
        H[(c << 8) + tid] = t * t;
    }
}

// ============ launch ==========================================================
extern "C" void kernel_launch(void* const* d_in, const int* in_sizes, int n_in,
                              void* d_out, int out_size, void* d_ws, size_t ws_size,
                              hipStream_t stream) {
    const float* x  = (const float*)d_in[0];
    const float* Wq = (const float*)d_in[1];
    const float* Wk = (const float*)d_in[2];
    const float* qg = (const float*)d_in[3];
    const float* qb = (const float*)d_in[4];
    const float* kg = (const float*)d_in[5];
    const float* kb = (const float*)d_in[6];
    const float* wC = (const float*)d_in[7];
    const float* wF = (const float*)d_in[8];
    const float* wS = (const float*)d_in[9];
    float* out = (float*)d_out;

    // workspace: region boundaries identical to proven round-11/12 layout.
    char* wsb = (char*)d_ws;
    u16*    UP   = (u16*)wsb;
    float*  qraw = (float*)wsb;
    float*  kraw = qraw + QK_N;
    float*  Gpart = (float*)(wsb + 2 * QK_N * sizeof(float));
    wsb += 3 * U_N * sizeof(u16);                               // 37.75 MB region
    u16*    qP    = (u16*)wsb;
    u16*    xP    = (u16*)wsb;   wsb += 3 * QK_N * sizeof(u16); // 12.6 MB region
    u16*    kP    = (u16*)wsb;   wsb += 3 * QK_N * sizeof(u16); // 12.6 MB region
    u16*    GPT   = (u16*)wsb;
    u16*    WP    = (u16*)wsb;   wsb += 3 * G_N * sizeof(u16);  // 9.4 MB region
    double* tg    = (double*)wsb;                                // 8.4 MB region
    double* part  = tg;                                          // 1 MB   (alias)
    double* csC   = tg + (size_t)4 * 16 * L_;                    // 32 KB  (alias)
    double* csS   = csC + (size_t)B_ * L_;                       // 32 KB  (alias)

    k_prep    <<<dim3(L_ + 7680), 256, 0, stream>>>(x, Wq, Wk, xP, WP, tg);
    k_proj    <<<dim3(8, 64, 2),  256, 0, stream>>>(xP, WP, qraw, kraw);
    k_lnrope  <<<dim3(B_ * L_),   128, 0, stream>>>(qraw, kraw, tg, qg, qb, kg, kb, qP, kP);
    k_gram    <<<dim3(8, 8, 12),  256, 0, stream>>>(qP, kP, Gpart);
    k_gsplitT <<<dim3(8, 8, 6),   256, 0, stream>>>(Gpart, GPT);
    k_u       <<<dim3(8, 32, 6),  256, 0, stream>>>(qP, kP, GPT, UP);
    k_scores  <<<dim3(32, 32, 6), 256, 0, stream>>>(qP, kP, UP, out);
    k_entmax  <<<dim3(3072),      256, 0, stream>>>(out + SLOT, 3 * B_ * L_, wC, wF, wS);
    k_colsum  <<<dim3(8, 16, 4),  256, 0, stream>>>(out, part);
    k_colred  <<<dim3(32),        256, 0, stream>>>(part, csC, csS);
    k_fin2    <<<dim3(B_ * L_),   256, 0, stream>>>(out, csC, csS);
}

// Round 15
// 564.201 us; speedup vs baseline: 1.1551x; 1.0206x over previous
//
#include <hip/hip_runtime.h>
#include <cstddef>
#include <math.h>

// ---------------- problem constants ----------------
#define B_   2
#define L_   2048
#define D_   512
#define E_   768
static const size_t LL   = (size_t)L_ * L_;
static const size_t SLOT = (size_t)B_ * LL;

#define QK_N  ((size_t)B_ * L_ * D_)       // 2097152
#define G1_N  ((size_t)512 * 512)          // 262144
#define G_N   ((size_t)6 * G1_N)           // 1572864
#define U_N   ((size_t)6 * L_ * D_)        // 6291456
#define X_N   ((size_t)4096 * 768)         // 3145728
#define W_N   ((size_t)512 * 768)          // 393216

typedef unsigned short u16;
typedef __attribute__((ext_vector_type(8))) _Float16 half8;  // 8 f16 (4 VGPR)
typedef __attribute__((ext_vector_type(4))) float f32x4;

// ---------------- f16x2 split of fp32, scaled residual ------------------------
// f = h0 + h1/4096 + r2, |r2| <= |f|*2^-24. L product tier dropped (r14, absmax
// still 0.0).
__device__ __forceinline__ void split2(float f, u16& h0, u16& h1) {
    _Float16 a = (_Float16)f;
    _Float16 b = (_Float16)((f - (float)a) * 4096.0f);
    h0 = __builtin_bit_cast(u16, a);
    h1 = __builtin_bit_cast(u16, b);
}

#define BKP 40   // LDS row pitch in u16 (pad: frag reads ~2-way banks)

// ============ plane-based stagers (16B global loads, 2 planes) ================
__device__ __forceinline__ void pstage_MK(const u16* __restrict__ P, size_t pstride, int ld,
                                          int r0, int k0, int tid, u16 S[2][64][BKP]) {
    int m = tid >> 2, kq = (tid & 3) << 3;                  // 8 u16 = 16B per thread
#pragma unroll
    for (int s = 0; s < 2; ++s) {
        const uint4 v = *reinterpret_cast<const uint4*>(
            P + (size_t)s * pstride + (size_t)(r0 + m) * ld + k0 + kq);
        *reinterpret_cast<uint4*>(&S[s][m][kq]) = v;        // 80B row pitch: 16B-aligned
    }
}
__device__ __forceinline__ void pstage_KM(const u16* __restrict__ P, size_t pstride, int ld,
                                          int r0, int k0, int tid, u16 S[2][64][BKP]) {
    int k = tid >> 3, mq = (tid & 7) << 3;
#pragma unroll
    for (int s = 0; s < 2; ++s) {
        const uint4 v = *reinterpret_cast<const uint4*>(
            P + (size_t)s * pstride + (size_t)(k0 + k) * ld + r0 + mq);
        const u16* pv = reinterpret_cast<const u16*>(&v);
#pragma unroll
        for (int c = 0; c < 8; ++c) S[s][mq + c][k] = pv[c];
    }
}

// ============ 3-tier f16x2 MFMA core, 16x16x32 (64x64 tile, BK=32) ============
// r12-proven loop (r13's 32x32 shape regressed: too few indep MFMA chains).
// PROM=true : H tier fp64-promoted EVERY step (r8 cadence; r7/r9 alternatives
//             regressed). Use for amplified intermediates (gram, U).
// PROM=false: H tier chains fp32 through MFMA (no promote VALU). Use where
//             output noise is NOT re-amplified (proj O(1) acc; final scores —
//             r1-calibrated transfer gives absmax ~3e-3 vs 2e-2 threshold).
template<bool AKM, bool BKM, bool PROM>
__device__ __forceinline__ void gemm_core(const u16* __restrict__ Ap, size_t Aps, int lda,
                                          const u16* __restrict__ Bp, size_t Bps, int ldb,
                                          int K, int m0, int n0, int tid,
                                          double outv[2][2][4]) {
    __shared__ u16 SA[2][64][BKP], SB[2][64][BKP];
    f32x4 accH[2][2], accM[2][2];
#pragma unroll
    for (int i = 0; i < 2; ++i)
#pragma unroll
        for (int j = 0; j < 2; ++j) {
            accH[i][j] = (f32x4){0.f, 0.f, 0.f, 0.f};
            accM[i][j] = (f32x4){0.f, 0.f, 0.f, 0.f};
        }
    double accD[2][2][4] = {};
    int lane = tid & 63, w = tid >> 6;
    int wm = (w & 1) << 5, wn = (w >> 1) << 5;
    int fr = lane & 15, ko = (lane >> 4) << 3;

    int nstep = K >> 5;
    for (int s = 0; s < nstep; ++s) {
        int k0 = s << 5;
        if (AKM) pstage_KM(Ap, Aps, lda, m0, k0, tid, SA); else pstage_MK(Ap, Aps, lda, m0, k0, tid, SA);
        if (BKM) pstage_KM(Bp, Bps, ldb, n0, k0, tid, SB); else pstage_MK(Bp, Bps, ldb, n0, k0, tid, SB);
        __syncthreads();
        half8 a[2][2], b[2][2];
#pragma unroll
        for (int f = 0; f < 2; ++f)
#pragma unroll
            for (int sp = 0; sp < 2; ++sp) {
                a[f][sp] = *reinterpret_cast<const half8*>(&SA[sp][wm + f * 16 + fr][ko]);
                b[f][sp] = *reinterpret_cast<const half8*>(&SB[sp][wn + f * 16 + fr][ko]);
            }
#pragma unroll
        for (int fi = 0; fi < 2; ++fi)
#pragma unroll
            for (int fj = 0; fj < 2; ++fj) {
                accH[fi][fj] = __builtin_amdgcn_mfma_f32_16x16x32_f16(a[fi][0], b[fj][0], accH[fi][fj], 0, 0, 0);
                accM[fi][fj] = __builtin_amdgcn_mfma_f32_16x16x32_f16(a[fi][0], b[fj][1], accM[fi][fj], 0, 0, 0);
                accM[fi][fj] = __builtin_amdgcn_mfma_f32_16x16x32_f16(a[fi][1], b[fj][0], accM[fi][fj], 0, 0, 0);
            }
        __syncthreads();
        if (PROM) {
#pragma unroll
            for (int fi = 0; fi < 2; ++fi)
#pragma unroll
                for (int fj = 0; fj < 2; ++fj) {
#pragma unroll
                    for (int r = 0; r < 4; ++r) accD[fi][fj][r] += (double)accH[fi][fj][r];
                    accH[fi][fj] = (f32x4){0.f, 0.f, 0.f, 0.f};
                }
        }
    }
    const double S1 = 1.0 / 4096.0;
#pragma unroll
    for (int fi = 0; fi < 2; ++fi)
#pragma unroll
        for (int fj = 0; fj < 2; ++fj)
#pragma unroll
            for (int r = 0; r < 4; ++r)
                outv[fi][fj][r] = (PROM ? accD[fi][fj][r] : (double)accH[fi][fj][r])
                                + (double)accM[fi][fj][r] * S1;
}

// ============ prep: RoPE trig table + input f16x2 split (merged launch) =======
__global__ __launch_bounds__(256) void k_prep(const float* __restrict__ x,
                                              const float* __restrict__ Wq,
                                              const float* __restrict__ Wk,
                                              u16* __restrict__ xP,
                                              u16* __restrict__ WP,
                                              double* __restrict__ tg) {
    int bx = blockIdx.x;
    if (bx < L_) {
        int l = bx, j = threadIdx.x;
        double e = (double)j * (1.0 / 256.0);
        double inv = pow(10000.0, -e);
        double ang = (double)l * inv;
        tg[(size_t)l * 512 + j] = cos(ang);
        tg[(size_t)l * 512 + 256 + j] = sin(ang);
        return;
    }
    size_t gid = (size_t)(bx - L_) * 256 + threadIdx.x;
    const size_t XH = X_N / 2, WH = W_N / 2;
    const float* src; u16* dst; size_t pn, off;
    if (gid < XH)            { src = x  + 2 * gid;              dst = xP;            pn = X_N; off = 2 * gid; }
    else if (gid < XH + WH)  { size_t g = gid - XH;      src = Wq + 2 * g; dst = WP;            pn = W_N; off = 2 * g; }
    else                     { size_t g = gid - XH - WH; src = Wk + 2 * g; dst = WP + 2 * W_N;  pn = W_N; off = 2 * g; }
    float2 v = *reinterpret_cast<const float2*>(src);
    u16 a0, a1, b0, b1;
    split2(v.x, a0, a1);
    split2(v.y, b0, b1);
    *reinterpret_cast<unsigned*>(dst + off)      = (unsigned)a0 | ((unsigned)b0 << 16);
    *reinterpret_cast<unsigned*>(dst + pn + off) = (unsigned)a1 | ((unsigned)b1 << 16);
}

// ============ k_proj: plane GEMM (fp32 H acc — O(1) magnitudes) ===============
__global__ __launch_bounds__(256) void k_proj(const u16* __restrict__ xP,
                                              const u16* __restrict__ WP,
                                              float* __restrict__ qraw,
                                              float* __restrict__ kraw) {
    int z = blockIdx.z;
    float* out = z ? kraw : qraw;
    const u16* Bp = WP + (size_t)z * 2 * W_N;
    int m0 = blockIdx.y * 64, n0 = blockIdx.x * 64;
    double ov[2][2][4];
    gemm_core<false, false, false>(xP, X_N, E_, Bp, W_N, E_, E_, m0, n0, threadIdx.x, ov);
    int lane = threadIdx.x & 63, w = threadIdx.x >> 6;
    int wm = (w & 1) << 5, wn = (w >> 1) << 5;
    int col = lane & 15, rbase = (lane >> 4) << 2;
#pragma unroll
    for (int fi = 0; fi < 2; ++fi)
#pragma unroll
        for (int fj = 0; fj < 2; ++fj)
#pragma unroll
            for (int r = 0; r < 4; ++r) {
                int mm = m0 + wm + fi * 16 + rbase + r;
                int nn = n0 + wn + fj * 16 + col;
                out[(size_t)mm * D_ + nn] = (float)ov[fi][fj][r];
            }
}

// ============ LayerNorm + RoPE (fp64) -> f16x2 planes, q&k in parallel ========
__global__ __launch_bounds__(256) void k_lnrope(const float* __restrict__ qraw,
                                                const float* __restrict__ kraw,
                                                const double* __restrict__ tg,
                                                const float* __restrict__ qg, const float* __restrict__ qb,
                                                const float* __restrict__ kg, const float* __restrict__ kb,
                                                u16* __restrict__ qP, u16* __restrict__ kP) {
    int row = blockIdx.x;           // b*2048 + l
    int l = row & (L_ - 1);
    int tid = threadIdx.x;
    int half = tid >> 7, t = tid & 127;      // half 0 -> q, half 1 -> k
    __shared__ double nrow[2][D_];
    __shared__ double red[8];
    __shared__ double cs_[256], sn_[256];
    {
        int j = tid & 255;
        if (tid < 256) { cs_[j] = tg[(size_t)l * 512 + j]; sn_[j] = tg[(size_t)l * 512 + 256 + j]; }
    }
    const float* rp = (half ? kraw : qraw) + (size_t)row * D_;
    const float* g  = half ? kg : qg;
    const float* bt = half ? kb : qb;
    u16* P = half ? kP : qP;
    float4 v = reinterpret_cast<const float4*>(rp)[t];
    double vv[4] = {(double)v.x, (double)v.y, (double)v.z, (double)v.w};
    double s = vv[0] + vv[1] + vv[2] + vv[3];
    double s2 = vv[0]*vv[0] + vv[1]*vv[1] + vv[2]*vv[2] + vv[3]*vv[3];
    for (int off = 32; off; off >>= 1) { s += __shfl_xor(s, off); s2 += __shfl_xor(s2, off); }
    int wv = tid >> 6;                       // waves 0,1 -> half 0; 2,3 -> half 1
    if ((tid & 63) == 0) { red[wv * 2] = s; red[wv * 2 + 1] = s2; }
    __syncthreads();
    double mu  = (red[half * 4 + 0] + red[half * 4 + 2]) * (1.0 / D_);
    double var = (red[half * 4 + 1] + red[half * 4 + 3]) * (1.0 / D_) - mu * mu;
    double rs = rsqrt(var + 1e-5);
    int d0 = t * 4;
    double o[4];
#pragma unroll
    for (int c = 0; c < 4; ++c) {
        int d = d0 + c;
        o[c] = (vv[c] - mu) * rs * (double)g[d] + (double)bt[d];
    }
#pragma unroll
    for (int c = 0; c < 4; ++c) nrow[half][d0 + c] = o[c];
    __syncthreads();
    u16 h[2][4];
#pragma unroll
    for (int c = 0; c < 4; ++c) {
        int d = d0 + c;
        double rot = (d < 256) ? -nrow[half][d + 256] : nrow[half][d - 256];
        float ov = (float)(nrow[half][d] * cs_[d & 255] + rot * sn_[d & 255]);
        split2(ov, h[0][c], h[1][c]);
    }
    size_t off = (size_t)row * D_ + d0;
#pragma unroll
    for (int sp = 0; sp < 2; ++sp)
        *reinterpret_cast<ushort4*>(P + sp * QK_N + off) = make_ushort4(h[sp][0], h[sp][1], h[sp][2], h[sp][3]);
}

// ============ Gram split-K=2: planes -> fp32 partials (PROM) ==================
__global__ __launch_bounds__(256) void k_gram(const u16* __restrict__ qP,
                                              const u16* __restrict__ kP,
                                              float* __restrict__ Gpart) {
    int zz = blockIdx.z, half = zz & 1, z = zz >> 1;
    int b = z / 3, m = z % 3;
    const u16* A  = ((m == 2) ? qP : kP) + (size_t)b * L_ * D_ + (size_t)half * (L_ / 2) * D_;
    const u16* Bp = ((m == 0) ? kP : qP) + (size_t)b * L_ * D_ + (size_t)half * (L_ / 2) * D_;
    int m0 = blockIdx.y * 64, n0 = blockIdx.x * 64;
    double ov[2][2][4];
    gemm_core<true, true, true>(A, QK_N, D_, Bp, QK_N, D_, L_ / 2, m0, n0, threadIdx.x, ov);
    float* Gg = Gpart + (size_t)half * G_N + (size_t)z * G1_N;
    int lane = threadIdx.x & 63, w = threadIdx.x >> 6;
    int wm = (w & 1) << 5, wn = (w >> 1) << 5;
    int col = lane & 15, rbase = (lane >> 4) << 2;
#pragma unroll
    for (int fi = 0; fi < 2; ++fi)
#pragma unroll
        for (int fj = 0; fj < 2; ++fj)
#pragma unroll
            for (int r = 0; r < 4; ++r) {
                int mm = m0 + wm + fi * 16 + rbase + r;
                int nn = n0 + wn + fj * 16 + col;
                Gg[(size_t)mm * 512 + nn] = (float)ov[fi][fj][r];
            }
}

// ============ sum partials + TRANSPOSE + split into G^T planes ================
__global__ __launch_bounds__(256) void k_gsplitT(const float* __restrict__ Gpart,
                                                 u16* __restrict__ GPT) {
    __shared__ float T[64][65];
    int z = blockIdx.z, d0 = blockIdx.y * 64, e0 = blockIdx.x * 64;
    const float* Ga = Gpart + (size_t)z * G1_N;
    const float* Gb = Ga + G_N;
    int tid = threadIdx.x;
#pragma unroll
    for (int i = 0; i < 16; ++i) {
        int idx = tid + i * 256;
        int r = idx >> 6, c = idx & 63;
        size_t o = (size_t)(d0 + r) * 512 + e0 + c;
        T[r][c] = Ga[o] + Gb[o];
    }
    __syncthreads();
    u16* Gz = GPT + (size_t)z * G1_N;
#pragma unroll
    for (int i = 0; i < 16; ++i) {
        int idx = tid + i * 256;
        int er = idx >> 6, dc = idx & 63;
        u16 h0, h1; split2(T[dc][er], h0, h1);
        size_t o = (size_t)(e0 + er) * 512 + d0 + dc;
        Gz[o] = h0; Gz[G_N + o] = h1;
    }
}

// ============ U = {q,q,k} @ G : planes -> U planes (PROM) =====================
__global__ __launch_bounds__(256) void k_u(const u16* __restrict__ qP,
                                           const u16* __restrict__ kP,
                                           const u16* __restrict__ GPT,
                                           u16* __restrict__ UP) {
    int z = blockIdx.z, b = z / 3, m = z % 3;
    const u16* A  = ((m == 2) ? kP : qP) + (size_t)b * L_ * D_;
    const u16* Bp = GPT + (size_t)z * G1_N;
    int m0 = blockIdx.y * 64, n0 = blockIdx.x * 64;
    double ov[2][2][4];
    gemm_core<false, false, true>(A, QK_N, D_, Bp, G_N, 512, D_, m0, n0, threadIdx.x, ov);
    int lane = threadIdx.x & 63, w = threadIdx.x >> 6;
    int wm = (w & 1) << 5, wn = (w >> 1) << 5;
    int col = lane & 15, rbase = (lane >> 4) << 2;
#pragma unroll
    for (int fi = 0; fi < 2; ++fi)
#pragma unroll
        for (int fj = 0; fj < 2; ++fj)
#pragma unroll
            for (int r = 0; r < 4; ++r) {
                float uf = (float)ov[fi][fj][r];
                int mm = m0 + wm + fi * 16 + rbase + r;
                int nn = n0 + wn + fj * 16 + col;
                size_t off = (size_t)z * ((size_t)L_ * D_) + (size_t)mm * D_ + nn;
                u16 h0, h1; split2(uf, h0, h1);
                UP[off] = h0; UP[U_N + off] = h1;
            }
}

// ============ scores = U @ {q,k,k}^T (fp32 H acc — low amplification) =========
__global__ __launch_bounds__(256) void k_scores(const u16* __restrict__ qP,
                                                const u16* __restrict__ kP,
                                                const u16* __restrict__ UP,
                                                float* __restrict__ out) {
    int z = blockIdx.z, b = z / 3, m = z % 3;
    const u16* A  = UP + (size_t)z * ((size_t)L_ * D_);
    const u16* Bp = ((m == 0) ? qP : kP) + (size_t)b * L_ * D_;
    int m0 = blockIdx.y * 64, n0 = blockIdx.x * 64;
    double ov[2][2][4];
    gemm_core<false, false, false>(A, U_N, D_, Bp, QK_N, D_, D_, m0, n0, threadIdx.x, ov);
    float* Co = out + (size_t)(1 + m) * SLOT + (size_t)b * LL;
    int lane = threadIdx.x & 63, w = threadIdx.x >> 6;
    int wm = (w & 1) << 5, wn = (w >> 1) << 5;
    int col = lane & 15, rbase = (lane >> 4) << 2;
#pragma unroll
    for (int fi = 0; fi < 2; ++fi)
#pragma unroll
        for (int fj = 0; fj < 2; ++fj)
#pragma unroll
            for (int r = 0; r < 4; ++r) {
                int mm = m0 + wm + fi * 16 + rbase + r;
                int nn = n0 + wn + fj * 16 + col;
                Co[(size_t)mm * L_ + nn] = (float)ov[fi][fj][r];
            }
}

// ============ entmax-1.5 (slots 1-3): fp32, 9 bisect + 3 Newton ===============
__global__ __launch_bounds__(256) void k_entmax(float* __restrict__ base, int nrows,
                                                const float* __restrict__ wC,
                                                const float* __restrict__ wF,
                                                const float* __restrict__ wS) {
    int tid = threadIdx.x;
    int lane = tid & 63;
    int r = blockIdx.x * 4 + (tid >> 6);
    if (r >= nrows) return;
    int m = r >> 12;                 // 4096 rows per matrix
    const float* wp = (m == 0) ? wC : (m == 1) ? wF : wS;
    float hw = (float)(1.0 / (1.0 + exp(-(double)wp[0])));   // 0.5 * w
    float* row = base + (size_t)r * L_;
    float v[32];
    float mx = -3.4e38f;
#pragma unroll
    for (int j = 0; j < 32; ++j) {
        v[j] = row[lane + (j << 6)];
        mx = fmaxf(mx, v[j]);
    }
    for (int off = 32; off; off >>= 1) mx = fmaxf(mx, __shfl_xor(mx, off));
    float z[32];
#pragma unroll
    for (int j = 0; j < 32; ++j) z[j] = hw * (v[j] - mx);
    float lo = -1.0f, hi = 0.0f;
    for (int it = 0; it < 9; ++it) {
        float tau = 0.5f * (lo + hi);
        float ssum = 0.0f;
#pragma unroll
        for (int j = 0; j < 32; ++j) {
            float t = fmaxf(z[j] - tau, 0.0f);
            ssum = fmaf(t, t, ssum);
        }
        for (int off = 32; off; off >>= 1) ssum += __shfl_xor(ssum, off);
        if (ssum >= 1.0f) lo = tau; else hi = tau;
    }
    float tau = lo;   // f(lo) >= 1; Newton on convex f approaches root from left
    for (int it = 0; it < 3; ++it) {
        float s1 = 0.0f, s2 = 0.0f;
#pragma unroll
        for (int j = 0; j < 32; ++j) {
            float t = fmaxf(z[j] - tau, 0.0f);
            s1 += t;
            s2 = fmaf(t, t, s2);
        }
        for (int off = 32; off; off >>= 1) { s1 += __shfl_xor(s1, off); s2 += __shfl_xor(s2, off); }
        float denom = 2.0f * s1;
        if (denom > 1e-30f) tau += fmaxf((s2 - 1.0f) / denom, 0.0f);
    }
#pragma unroll
    for (int j = 0; j < 32; ++j) {
        float t = fmaxf(z[j] - tau, 0.0f);
        row[lane + (j << 6)] = fminf(t * t, 1.0f - 1e-6f);
    }
}

// ============ column sums: partials (deterministic, parallel) =================
__global__ __launch_bounds__(256) void k_colsum(const float* __restrict__ out,
                                                double* __restrict__ part) {
    int bz = blockIdx.z, which = bz >> 1, b = bz & 1;
    const float* mat = out + (size_t)(which ? 3 : 1) * SLOT + (size_t)b * LL;
    int j = blockIdx.x * 256 + threadIdx.x;
    int r0 = blockIdx.y * 128;
    double s = 0.0;
#pragma unroll 8
    for (int r = 0; r < 128; ++r) s += (double)mat[(size_t)(r0 + r) * L_ + j];
    part[((size_t)bz * 16 + blockIdx.y) * L_ + j] = s;
}

__global__ __launch_bounds__(256) void k_colred(const double* __restrict__ part,
                                                double* __restrict__ csC,
                                                double* __restrict__ csS) {
    int g = blockIdx.x * 256 + threadIdx.x;   // 0..8191 = bz*2048 + j
    int bz = g >> 11, j = g & (L_ - 1);
    int which = bz >> 1, b = bz & 1;
    double s = 0.0;
#pragma unroll
    for (int c = 0; c < 16; ++c) s += part[((size_t)bz * 16 + c) * L_ + j];
    (which ? csS : csC)[b * L_ + j] = s;
}

// ============ fused finalize + entmax(H): one block per row ===================
__global__ __launch_bounds__(256) void k_fin2(float* __restrict__ out,
                                              const double* __restrict__ csC,
                                              const double* __restrict__ csS) {
    int row = blockIdx.x;               // b*2048 + i
    int i = row & (L_ - 1), b = row >> 11;
    size_t ro = (size_t)row * L_;
    float* H  = out + ro;
    float* pC = out + SLOT + ro;
    float* pF = out + 2 * SLOT + ro;
    float* pS = out + 3 * SLOT + ro;
    const double* cc = csC + b * L_;
    const double* cs = csS + b * L_;
    int tid = threadIdx.x, lane = tid & 63, wv = tid >> 6;
    __shared__ float red[4], red2[4];
    const double A1 = 1.0 - 2e-6;
    float h[8];
    float mx = -3.4e38f;
#pragma unroll
    for (int c = 0; c < 8; ++c) {
        int j = (c << 8) + tid;
        double cv = (double)pC[j] * rsqrt(cc[j] + 1e-6);
        double fv = (double)pF[j];
        double sv = (double)pS[j] * rsqrt(cs[j] + 1e-6);
        cv = fmax(A1 * cv + 1e-6, 1e-6);
        fv = fmax(A1 * fv + 1e-6, 1e-6);
        sv = fmax(A1 * sv + 1e-6, 1e-6);
        pC[j] = (float)cv; pF[j] = (float)fv; pS[j] = (float)sv;
        h[c] = (j == i) ? -1e9f : logf((float)(cv * fv * sv)) * (1.0f / 3.0f);
        mx = fmaxf(mx, h[c]);
    }
    for (int off = 32; off; off >>= 1) mx = fmaxf(mx, __shfl_xor(mx, off));
    if (lane == 0) red[wv] = mx;
    __syncthreads();
    mx = fmaxf(fmaxf(red[0], red[1]), fmaxf(red[2], red[3]));
    __syncthreads();
    float z[8];
#pragma unroll
    for (int c = 0; c < 8; ++c) z[c] = 0.5f * (h[c] - mx);
    float lo = -1.0f, hi = 0.0f;
    for (int it = 0; it < 9; ++it) {
        float tau = 0.5f * (lo + hi);
        float ssum = 0.0f;
#pragma unroll
        for (int c = 0; c < 8; ++c) {
            float t = fmaxf(z[c] - tau, 0.0f);
            ssum = fmaf(t, t, ssum);
        }
        for (int off = 32; off; off >>= 1) ssum += __shfl_xor(ssum, off);
        if (lane == 0) red[wv] = ssum;
        __syncthreads();
        ssum = red[0] + red[1] + red[2] + red[3];
        __syncthreads();
        if (ssum >= 1.0f) lo = tau; else hi = tau;
    }
    float tau = lo;
    for (int it = 0; it < 3; ++it) {
        float s1 = 0.0f, s2 = 0.0f;
#pragma unroll
        for (int c = 0; c < 8; ++c) {
            float t = fmaxf(z[c] - tau, 0.0f);
            s1 += t;
            s2 = fmaf(t, t, s2);
        }
        for (int off = 32; off; off >>= 1) { s1 += __shfl_xor(s1, off); s2 += __shfl_xor(s2, off); }
        if (lane == 0) { red[wv] = s1; red2[wv] = s2; }
        __syncthreads();
        s1 = red[0] + red[1] + red[2] + red[3];
        s2 = red2[0] + red2[1] + red2[2] + red2[3];
        __syncthreads();
        float denom = 2.0f * s1;
        if (denom > 1e-30f) tau += fmaxf((s2 - 1.0f) / denom, 0.0f);
    }
#pragma unroll
    for (int c = 0; c < 8; ++c) {
        float t = fmaxf(z[c] - tau, 0.0f);
        H[(c << 8) + tid] = t * t;
    }
}

// ============ launch ==========================================================
extern "C" void kernel_launch(void* const* d_in, const int* in_sizes, int n_in,
                              void* d_out, int out_size, void* d_ws, size_t ws_size,
                              hipStream_t stream) {
    const float* x  = (const float*)d_in[0];
    const float* Wq = (const float*)d_in[1];
    const float* Wk = (const float*)d_in[2];
    const float* qg = (const float*)d_in[3];
    const float* qb = (const float*)d_in[4];
    const float* kg = (const float*)d_in[5];
    const float* kb = (const float*)d_in[6];
    const float* wC = (const float*)d_in[7];
    const float* wF = (const float*)d_in[8];
    const float* wS = (const float*)d_in[9];
    float* out = (float*)d_out;

    // workspace: region boundaries identical to proven round-11..14 layout.
    char* wsb = (char*)d_ws;
    u16*    UP   = (u16*)wsb;
    float*  qraw = (float*)wsb;
    float*  kraw = qraw + QK_N;
    float*  Gpart = (float*)(wsb + 2 * QK_N * sizeof(float));
    wsb += 3 * U_N * sizeof(u16);                               // 37.75 MB region
    u16*    qP    = (u16*)wsb;
    u16*    xP    = (u16*)wsb;   wsb += 3 * QK_N * sizeof(u16); // 12.6 MB region
    u16*    kP    = (u16*)wsb;   wsb += 3 * QK_N * sizeof(u16); // 12.6 MB region
    u16*    GPT   = (u16*)wsb;
    u16*    WP    = (u16*)wsb;   wsb += 3 * G_N * sizeof(u16);  // 9.4 MB region
    double* tg    = (double*)wsb;                                // 8.4 MB region
    double* part  = tg;                                          // 1 MB   (alias)
    double* csC   = tg + (size_t)4 * 16 * L_;                    // 32 KB  (alias)
    double* csS   = csC + (size_t)B_ * L_;                       // 32 KB  (alias)

    k_prep    <<<dim3(L_ + 7680), 256, 0, stream>>>(x, Wq, Wk, xP, WP, tg);
    k_proj    <<<dim3(8, 64, 2),  256, 0, stream>>>(xP, WP, qraw, kraw);
    k_lnrope  <<<dim3(B_ * L_),   256, 0, stream>>>(qraw, kraw, tg, qg, qb, kg, kb, qP, kP);
    k_gram    <<<dim3(8, 8, 12),  256, 0, stream>>>(qP, kP, Gpart);
    k_gsplitT <<<dim3(8, 8, 6),   256, 0, stream>>>(Gpart, GPT);
    k_u       <<<dim3(8, 32, 6),  256, 0, stream>>>(qP, kP, GPT, UP);
    k_scores  <<<dim3(32, 32, 6), 256, 0, stream>>>(qP, kP, UP, out);
    k_entmax  <<<dim3(3072),      256, 0, stream>>>(out + SLOT, 3 * B_ * L_, wC, wF, wS);
    k_colsum  <<<dim3(8, 16, 4),  256, 0, stream>>>(out, part);
    k_colred  <<<dim3(32),        256, 0, stream>>>(part, csC, csS);
    k_fin2    <<<dim3(B_ * L_),   256, 0, stream>>>(out, csC, csS);
}